// Round 3
// baseline (718.889 us; speedup 1.0000x reference)
//
#include <hip/hip_runtime.h>
#include <math.h>

// FrankWolfePolicyImprovement, fused: 4096 problems, one wave (64 lanes) each.
// Phases (single kernel, A resident in LDS throughout):
//   1. anchor QP  (Schur-reduced d=68 ADMM, 80 it, Sinv rows in VGPRs)
//   2. tanh MLP gradient (W1 coalesced float4; W1T pre-packed for coalesced float4)
//   3. row-normalize A in LDS, LMO QP (d=64 ADMM, 80 it)
//   4. blend + store
// Register budget: __launch_bounds__(64,3) -> 170 regs/wave. Live set trimmed to
// ~125 (acol loaded AFTER gj_invert; S-build reads ak from LDS) so everything
// stays in arch VGPRs -- round-2's 64-VGPR + AGPR-spill (42 MB scratch writes)
// was the 3.5x VALU inflation.
// Wave-internal exchanges (v2/v3/r2/s) via readlane/shfl: 2 syncthreads/iter.

constexpr float SIG  = 1e-6f;
constexpr float C2   = 1.0f / (4.0f + 1e-6f);   // 1/(4+sigma): slack Schur diag
constexpr int   ITRS = 80;
constexpr int   LDA  = 68;                       // LDS stride for A (16B-aligned rows)

__device__ __forceinline__ float rl(float v, int lane) {
  return __uint_as_float(__builtin_amdgcn_readlane(__float_as_uint(v), lane));
}

// In-place Gauss-Jordan inverse of SPD matrix, column layout with rotation:
// on entry lane j holds Cm[i] = S[i][j]; on exit Cm[i] = Sinv[i][j] (= row j).
// Pivot column via readlane (uniform SGPR index); row-rotation fused into the
// shifted write so the p-loop stays rolled.
__device__ __forceinline__ void gj_invert(float (&Cm)[64], int t) {
#pragma unroll 1
  for (int p = 0; p < 64; ++p) {
    float piv = 1.0f / rl(Cm[0], p);
    bool  isP = (t == p);
    float sc  = Cm[0] * piv;
    float a    = isP ? (1.0f + piv) : sc;
    float last = isP ? piv          : sc;
#pragma unroll
    for (int m = 1; m < 64; ++m) {
      float s = rl(Cm[m], p);
      Cm[m - 1] = fmaf(-s, a, Cm[m]);
    }
    Cm[63] = last;
  }
}

__global__ __launch_bounds__(64, 3) void fw_kernel(
    const float* __restrict__ xraw, const float* __restrict__ A,
    const float* __restrict__ b, const float* __restrict__ W1,
    const float* __restrict__ W1T, const float* __restrict__ w2,
    float* __restrict__ out) {
  const int n = blockIdx.x, t = threadIdx.x;
  const float* Ap = A + (size_t)n * 2048;

  __shared__ __align__(16) float lsA[32 * LDA];   // 8704 B
  __shared__ __align__(16) float sbuf[256];       // 1024 B, multi-purpose
  float* lst1 = sbuf;            // [64]  ADMM t1 broadcast
  float* lsx  = sbuf + 64;       // [64]  ADMM x broadcast
  float* lsrn = sbuf + 176;      // [32]  1/rownorm (LMO phase)
  // MLP phase reuses sbuf[0..255] as the u-vector.

  // ---- stage A into LDS (float4 both sides) ----
  const float4* Apv = (const float4*)Ap;
#pragma unroll
  for (int jj = 0; jj < 8; ++jj) {
    float4 a4 = Apv[t + 64 * jj];
    int k = (t >> 4) + 4 * jj;        // row
    int col = 4 * (t & 15);
    *((float4*)&lsA[k * LDA + col]) = a4;
  }
  __syncthreads();

  const int r = t & 31, c0 = (t >> 5) << 5;

  // ================= anchor QP: build S, invert =================
  // S column t: (2+sig)I + A^T A - C2 * As^T As  (As = rows 28..31)
  float Cm[64];
#pragma unroll
  for (int i = 0; i < 64; ++i) Cm[i] = 0.f;
#pragma unroll 1
  for (int k = 0; k < 32; ++k) {
    float wk = (k < 28) ? 1.0f : (1.0f - C2);
    float ak = wk * lsA[k * LDA + t];
#pragma unroll
    for (int ii = 0; ii < 16; ++ii) {
      float4 a4 = *((const float4*)&lsA[k * LDA + 4 * ii]);
      Cm[4 * ii + 0] = fmaf(ak, a4.x, Cm[4 * ii + 0]);
      Cm[4 * ii + 1] = fmaf(ak, a4.y, Cm[4 * ii + 1]);
      Cm[4 * ii + 2] = fmaf(ak, a4.z, Cm[4 * ii + 2]);
      Cm[4 * ii + 3] = fmaf(ak, a4.w, Cm[4 * ii + 3]);
    }
  }
#pragma unroll
  for (int i = 0; i < 64; ++i) Cm[i] += (i == t) ? (2.0f + SIG) : 0.0f;

  gj_invert(Cm, t);  // Cm[j] = Sinv[t][j]

  float acol[32];
#pragma unroll
  for (int k = 0; k < 32; ++k) acol[k] = lsA[k * LDA + t];   // A[k][t]

  const float xf = xraw[(size_t)n * 64 + t];
  const float bl = (t < 32) ? b[(size_t)n * 32 + t] : 0.f;

  // ================= anchor ADMM =================
  float x_loc = 0.f, s_loc = 0.f;
  float z1 = 0.f, y1 = 0.f;                       // rows t: l=0,u=inf
  float z2 = (t < 32) ? fminf(0.f, bl) : 0.f;     // rows 64+t: l=-inf,u=b (lanes<32)
  float y2 = 0.f;
  float z3 = 0.f, y3 = 0.f;                       // lanes 32..35: slack bound rows

#pragma unroll 1
  for (int it = 0; it < ITRS; ++it) {
    float v2 = z2 - y2;                            // valid lanes<32
    float v3 = __shfl(z3 - y3, t + 4);             // lanes 28..31 <- lanes 32..35

    // rhs x-part: sig*x + xf + v1 + A^T v2   (4-way ILP)
    float r10 = fmaf(SIG, x_loc, xf) + (z1 - y1);
    float r11 = 0.f, r12 = 0.f, r13 = 0.f;
#pragma unroll
    for (int k = 0; k < 32; k += 4) {
      r10 = fmaf(acol[k + 0], rl(v2, k + 0), r10);
      r11 = fmaf(acol[k + 1], rl(v2, k + 1), r11);
      r12 = fmaf(acol[k + 2], rl(v2, k + 2), r12);
      r13 = fmaf(acol[k + 3], rl(v2, k + 3), r13);
    }
    float r1 = (r10 + r11) + (r12 + r13);

    // rhs s-part (meaningful lanes 28..31): sig*s - v[92+i] + v[96+i]
    float r2v = fmaf(SIG, s_loc, v3 - v2);

    // t1 = r1 + C2 * As^T r2
    float acc = 0.f;
    acc = fmaf(acol[28], rl(r2v, 28), acc);
    acc = fmaf(acol[29], rl(r2v, 29), acc);
    acc = fmaf(acol[30], rl(r2v, 30), acc);
    acc = fmaf(acol[31], rl(r2v, 31), acc);
    lst1[t] = fmaf(C2, acc, r1);
    __syncthreads();

    // x = Sinv * t1  (4-way ILP)
    float xn0 = 0.f, xn1 = 0.f, xn2 = 0.f, xn3 = 0.f;
#pragma unroll
    for (int jj = 0; jj < 16; ++jj) {
      float4 t4 = ((const float4*)lst1)[jj];
      xn0 = fmaf(Cm[4 * jj + 0], t4.x, xn0);
      xn1 = fmaf(Cm[4 * jj + 1], t4.y, xn1);
      xn2 = fmaf(Cm[4 * jj + 2], t4.z, xn2);
      xn3 = fmaf(Cm[4 * jj + 3], t4.w, xn3);
    }
    float xn = (xn0 + xn1) + (xn2 + xn3);
    x_loc = xn;
    lsx[t] = xn;
    __syncthreads();

    // (A x)[r]: split halves + combine
    float pa0 = 0.f, pa1 = 0.f, pa2 = 0.f, pa3 = 0.f;
#pragma unroll
    for (int jj = 0; jj < 8; ++jj) {
      float4 x4 = ((const float4*)(lsx + c0))[jj];
      float4 a4 = *((const float4*)&lsA[r * LDA + c0 + 4 * jj]);
      pa0 = fmaf(a4.x, x4.x, pa0);
      pa1 = fmaf(a4.y, x4.y, pa1);
      pa2 = fmaf(a4.z, x4.z, pa2);
      pa3 = fmaf(a4.w, x4.w, pa3);
    }
    float pa = (pa0 + pa1) + (pa2 + pa3);
    pa += __shfl_xor(pa, 32);

    // s = C2*(r2 + As x)  (meaningful lanes 28..31)
    float s_new = C2 * (r2v + pa);

    // z,y updates
    { float q1 = xn + y1; z1 = fmaxf(q1, 0.f); y1 = q1 - z1; }
    if (t < 32) {
      float Cx2 = pa - ((t >= 28) ? s_new : 0.f);  // rows 92..95: As x - s
      float q2 = Cx2 + y2; z2 = fminf(q2, bl); y2 = q2 - z2;
    }
    s_loc = s_new;
    float s_from = __shfl(s_new, t - 4);           // lanes 32..35 <- 28..31
    { float q3 = s_from + y3; z3 = fmaxf(q3, 0.f); y3 = q3 - z3; }
  }
  const float xfeas_r = x_loc;

  // ================= MLP gradient =================
  // h-cols 4t..4t+3: x broadcast via readlane, W1 float4 coalesced
  float4 hacc = make_float4(0.f, 0.f, 0.f, 0.f);
  const float4* W1v = (const float4*)W1;
#pragma unroll 4
  for (int j = 0; j < 64; ++j) {
    float xj = rl(x_loc, j);
    float4 w = W1v[j * 64 + t];
    hacc.x = fmaf(xj, w.x, hacc.x);
    hacc.y = fmaf(xj, w.y, hacc.y);
    hacc.z = fmaf(xj, w.z, hacc.z);
    hacc.w = fmaf(xj, w.w, hacc.w);
  }
  float4 wv = ((const float4*)w2)[t];
  float hx, u0, u1, u2, u3;
  hx = tanhf(hacc.x); u0 = (1.f - hx * hx) * wv.x;
  hx = tanhf(hacc.y); u1 = (1.f - hx * hx) * wv.y;
  hx = tanhf(hacc.z); u2 = (1.f - hx * hx) * wv.z;
  hx = tanhf(hacc.w); u3 = (1.f - hx * hx) * wv.w;
  __syncthreads();                       // ADMM lst1/lsx readers done
  ((float4*)sbuf)[t] = make_float4(u0, u1, u2, u3);   // sbuf = u[256]
  __syncthreads();

  // g[t] = sum_c W1[t][c]*u[c]; W1T pre-packed: W1T4[c4*64+t] = W1[t][4c4..4c4+3]
  float g0 = 0.f, g1 = 0.f, g2 = 0.f, g3 = 0.f;
  const float4* L4 = (const float4*)W1T;
#pragma unroll 4
  for (int c4 = 0; c4 < 64; ++c4) {
    float4 u4 = ((const float4*)sbuf)[c4];   // broadcast
    float4 w4 = L4[c4 * 64 + t];             // coalesced
    g0 = fmaf(w4.x, u4.x, g0);
    g1 = fmaf(w4.y, u4.y, g1);
    g2 = fmaf(w4.z, u4.z, g2);
    g3 = fmaf(w4.w, u4.w, g3);
  }
  const float gl = (g0 + g1) + (g2 + g3);

  // ================= row norms, normalize A in LDS =================
  float pr0 = 0.f, pr1 = 0.f, pr2 = 0.f, pr3 = 0.f;
#pragma unroll
  for (int jj = 0; jj < 8; ++jj) {
    float4 a4 = *((const float4*)&lsA[r * LDA + c0 + 4 * jj]);
    pr0 = fmaf(a4.x, a4.x, pr0);
    pr1 = fmaf(a4.y, a4.y, pr1);
    pr2 = fmaf(a4.z, a4.z, pr2);
    pr3 = fmaf(a4.w, a4.w, pr3);
  }
  float pr = (pr0 + pr1) + (pr2 + pr3);
  pr += __shfl_xor(pr, 32);
  __syncthreads();                       // u-readers done before sbuf+176 write
  if (t < 32) lsrn[t] = 1.0f / fmaxf(sqrtf(pr), 1e-12f);   // store reciprocal
  __syncthreads();
#pragma unroll
  for (int k = 0; k < 32; ++k) lsA[k * LDA + t] *= lsrn[k];
  const float bn = (t < 32) ? bl * lsrn[t] : 0.f;
  __syncthreads();

  // ================= LMO QP: build M, invert =================
#pragma unroll
  for (int i = 0; i < 64; ++i) Cm[i] = 0.f;
#pragma unroll 1
  for (int k = 0; k < 32; ++k) {
    float ak = lsA[k * LDA + t];
#pragma unroll
    for (int ii = 0; ii < 16; ++ii) {
      float4 a4 = *((const float4*)&lsA[k * LDA + 4 * ii]);
      Cm[4 * ii + 0] = fmaf(ak, a4.x, Cm[4 * ii + 0]);
      Cm[4 * ii + 1] = fmaf(ak, a4.y, Cm[4 * ii + 1]);
      Cm[4 * ii + 2] = fmaf(ak, a4.z, Cm[4 * ii + 2]);
      Cm[4 * ii + 3] = fmaf(ak, a4.w, Cm[4 * ii + 3]);
    }
  }
#pragma unroll
  for (int i = 0; i < 64; ++i) Cm[i] += (i == t) ? (1.0f + 1e-4f + SIG) : 0.0f;

  gj_invert(Cm, t);

#pragma unroll
  for (int k = 0; k < 32; ++k) acol[k] = lsA[k * LDA + t];   // normalized cols

  // ================= LMO ADMM =================
  x_loc = 0.f; z1 = 0.f; y1 = 0.f;
  z2 = (t < 32) ? fminf(0.f, bn) : 0.f;
  y2 = 0.f;

#pragma unroll 1
  for (int it = 0; it < ITRS; ++it) {
    float v2 = z2 - y2;
    float r10 = fmaf(SIG, x_loc, gl) + (z1 - y1);
    float r11 = 0.f, r12 = 0.f, r13 = 0.f;
#pragma unroll
    for (int k = 0; k < 32; k += 4) {
      r10 = fmaf(acol[k + 0], rl(v2, k + 0), r10);
      r11 = fmaf(acol[k + 1], rl(v2, k + 1), r11);
      r12 = fmaf(acol[k + 2], rl(v2, k + 2), r12);
      r13 = fmaf(acol[k + 3], rl(v2, k + 3), r13);
    }
    lst1[t] = (r10 + r11) + (r12 + r13);
    __syncthreads();

    float xn0 = 0.f, xn1 = 0.f, xn2 = 0.f, xn3 = 0.f;
#pragma unroll
    for (int jj = 0; jj < 16; ++jj) {
      float4 t4 = ((const float4*)lst1)[jj];
      xn0 = fmaf(Cm[4 * jj + 0], t4.x, xn0);
      xn1 = fmaf(Cm[4 * jj + 1], t4.y, xn1);
      xn2 = fmaf(Cm[4 * jj + 2], t4.z, xn2);
      xn3 = fmaf(Cm[4 * jj + 3], t4.w, xn3);
    }
    float xn = (xn0 + xn1) + (xn2 + xn3);
    x_loc = xn;
    lsx[t] = xn;
    __syncthreads();

    float pa0 = 0.f, pa1 = 0.f, pa2 = 0.f, pa3 = 0.f;
#pragma unroll
    for (int jj = 0; jj < 8; ++jj) {
      float4 x4 = ((const float4*)(lsx + c0))[jj];
      float4 a4 = *((const float4*)&lsA[r * LDA + c0 + 4 * jj]);
      pa0 = fmaf(a4.x, x4.x, pa0);
      pa1 = fmaf(a4.y, x4.y, pa1);
      pa2 = fmaf(a4.z, x4.z, pa2);
      pa3 = fmaf(a4.w, x4.w, pa3);
    }
    float pa = (pa0 + pa1) + (pa2 + pa3);
    pa += __shfl_xor(pa, 32);

    { float q1 = xn + y1; z1 = fmaxf(q1, 0.f); y1 = q1 - z1; }
    if (t < 32) { float q2 = pa + y2; z2 = fminf(q2, bn); y2 = q2 - z2; }
  }

  out[(size_t)n * 64 + t] = fmaf(0.1f, x_loc, 0.9f * xfeas_r);
}

// ---- W1 re-pack: W1T[c4*256 + t*4 + j] = W1[t*256 + 4*c4 + j] (once) ----
__global__ void w1t_kernel(const float* __restrict__ W1, float* __restrict__ W1T) {
  int idx = blockIdx.x * 256 + threadIdx.x;
  if (idx < 64 * 256) {
    int c4 = idx >> 8, rem = idx & 255, tt = rem >> 2, j = rem & 3;
    W1T[idx] = W1[tt * 256 + 4 * c4 + j];
  }
}

extern "C" void kernel_launch(void* const* d_in, const int* in_sizes, int n_in,
                              void* d_out, int out_size, void* d_ws, size_t ws_size,
                              hipStream_t stream) {
  const float* xraw = (const float*)d_in[0];  // [N,64]
  const float* A    = (const float*)d_in[1];  // [N,32,64]
  const float* b    = (const float*)d_in[2];  // [N,32]
  const float* W1   = (const float*)d_in[3];  // [64,256]
  const float* w2   = (const float*)d_in[4];  // [256]
  float* out = (float*)d_out;

  const int nprob = in_sizes[0] / 64;
  float* W1T = (float*)d_ws;                  // 16384 floats

  w1t_kernel<<<64, 256, 0, stream>>>(W1, W1T);
  fw_kernel<<<nprob, 64, 0, stream>>>(xraw, A, b, W1, W1T, w2, out);
}

// Round 4
// 634.598 us; speedup vs baseline: 1.1328x; 1.1328x over previous
//
#include <hip/hip_runtime.h>
#include <math.h>

// FrankWolfePolicyImprovement, fused: 4096 problems, one wave (64 lanes) each.
// Phases (single kernel, A resident in LDS throughout):
//   1. anchor QP  (Schur-reduced d=68 ADMM, 80 it, Sinv rows in VGPRs)
//   2. tanh MLP gradient (W1 coalesced float4; W1T pre-packed float4)
//   3. LMO QP on row-normalized A (normalization folded into register scaling)
//   4. blend + store
//
// Round-4 design notes (from rocprof evidence):
//  - VALU-issue-bound. All wave-internal broadcasts go through the LDS pipe
//    (wave-uniform-address float4 reads are conflict-free broadcasts, ~free)
//    instead of v_readlane chains (VALU + SGPR hazards) -- round 3 regressed
//    by doing the opposite.
//  - __launch_bounds__(64,2): 256-reg budget so Cm[64]+acol[32]+arow[32]+state
//    (~190) allocates as pure arch VGPRs. Round 2/3 showed smaller budgets make
//    the allocator split into AGPRs (accvgpr_read/write per access) or spill.
//  - One wave per block: __syncthreads is near-free, used only to order LDS.

constexpr float SIG  = 1e-6f;
constexpr float C2   = 1.0f / (4.0f + 1e-6f);   // 1/(4+sigma): slack Schur diag
constexpr int   ITRS = 80;
constexpr int   LDA  = 68;                       // LDS stride for A (16B-aligned rows)

__device__ __forceinline__ float rl(float v, int lane) {
  return __uint_as_float(__builtin_amdgcn_readlane(__float_as_uint(v), lane));
}

// In-place Gauss-Jordan inverse of SPD matrix, column layout with rotation:
// on entry lane j holds Cm[i] = S[i][j]; on exit Cm[i] = Sinv[i][j] (= row j).
// Pivot column via readlane (uniform SGPR index); row-rotation fused into the
// shifted write so the p-loop stays rolled.
__device__ __forceinline__ void gj_invert(float (&Cm)[64], int t) {
#pragma unroll 1
  for (int p = 0; p < 64; ++p) {
    float piv = 1.0f / rl(Cm[0], p);
    bool  isP = (t == p);
    float sc  = Cm[0] * piv;
    float a    = isP ? (1.0f + piv) : sc;
    float last = isP ? piv          : sc;
#pragma unroll
    for (int m = 1; m < 64; ++m) {
      float s = rl(Cm[m], p);
      Cm[m - 1] = fmaf(-s, a, Cm[m]);
    }
    Cm[63] = last;
  }
}

__global__ __launch_bounds__(64, 2) void fw_kernel(
    const float* __restrict__ xraw, const float* __restrict__ A,
    const float* __restrict__ b, const float* __restrict__ W1,
    const float* __restrict__ W1T, const float* __restrict__ w2,
    float* __restrict__ out) {
  const int n = blockIdx.x, t = threadIdx.x;
  const float* Ap = A + (size_t)n * 2048;

  __shared__ __align__(16) float lsA[32 * LDA];   // 8704 B, raw A (never rewritten)
  __shared__ __align__(16) float sbuf[256];       // 1024 B, multi-purpose
  float* lst1 = sbuf;            // [64]  ADMM t1 broadcast
  float* lsx  = sbuf + 64;       // [64]  ADMM x broadcast
  float* lsv2 = sbuf + 128;      // [32]  ADMM v2 broadcast
  float* lsrn = sbuf + 176;      // [32]  1/rownorm (LMO phase)
  // MLP phase reuses sbuf[0..255] as the u-vector.

  // ---- stage A into LDS (float4 both sides) ----
  const float4* Apv = (const float4*)Ap;
#pragma unroll
  for (int jj = 0; jj < 8; ++jj) {
    float4 a4 = Apv[t + 64 * jj];
    int k = (t >> 4) + 4 * jj;        // row
    int col = 4 * (t & 15);
    *((float4*)&lsA[k * LDA + col]) = a4;
  }
  __syncthreads();

  const int r = t & 31, c0 = (t >> 5) << 5;

  float acol[32], arow[32];
#pragma unroll
  for (int k = 0; k < 32; ++k) acol[k] = lsA[k * LDA + t];        // A[k][t]
#pragma unroll
  for (int j = 0; j < 32; ++j) arow[j] = lsA[r * LDA + c0 + j];   // A[r][c0+j]

  // ================= anchor QP: build S, invert =================
  // S column t: (2+sig)I + A^T A - C2 * As^T As  (As = rows 28..31)
  float Cm[64];
#pragma unroll
  for (int i = 0; i < 64; ++i) Cm[i] = 0.f;
#pragma unroll 1
  for (int k = 0; k < 32; ++k) {
    float wk = (k < 28) ? 1.0f : (1.0f - C2);
    float ak = wk * acol[k];
#pragma unroll
    for (int ii = 0; ii < 16; ++ii) {
      float4 a4 = *((const float4*)&lsA[k * LDA + 4 * ii]);  // uniform addr: broadcast
      Cm[4 * ii + 0] = fmaf(ak, a4.x, Cm[4 * ii + 0]);
      Cm[4 * ii + 1] = fmaf(ak, a4.y, Cm[4 * ii + 1]);
      Cm[4 * ii + 2] = fmaf(ak, a4.z, Cm[4 * ii + 2]);
      Cm[4 * ii + 3] = fmaf(ak, a4.w, Cm[4 * ii + 3]);
    }
  }
#pragma unroll
  for (int i = 0; i < 64; ++i) Cm[i] += (i == t) ? (2.0f + SIG) : 0.0f;

  gj_invert(Cm, t);  // Cm[j] = Sinv[t][j]

  const float xf = xraw[(size_t)n * 64 + t];
  const float bl = (t < 32) ? b[(size_t)n * 32 + t] : 0.f;

  // ================= anchor ADMM =================
  float x_loc = 0.f, s_loc = 0.f;
  float z1 = 0.f, y1 = 0.f;                       // rows t: l=0,u=inf
  float z2 = (t < 32) ? fminf(0.f, bl) : 0.f;     // rows 64+r: l=-inf,u=b (lanes<32)
  float y2 = 0.f;
  float z3 = 0.f, y3 = 0.f;                       // lanes 32..35: slack bound rows

#pragma unroll 1
  for (int it = 0; it < ITRS; ++it) {
    float v2 = z2 - y2;                            // meaningful lanes<32
    if (t < 32) lsv2[t] = v2;
    float v3 = __shfl(z3 - y3, t + 4);             // lanes 28..31 <- lanes 32..35
    __syncthreads();

    // rhs x-part: sig*x + xf + v1 + A^T v2   (v2 via LDS broadcast, 4-way ILP)
    float r10 = fmaf(SIG, x_loc, xf) + (z1 - y1);
    float r11 = 0.f, r12 = 0.f, r13 = 0.f;
#pragma unroll
    for (int kk = 0; kk < 8; ++kk) {
      float4 v4 = ((const float4*)lsv2)[kk];       // broadcast
      r10 = fmaf(acol[4 * kk + 0], v4.x, r10);
      r11 = fmaf(acol[4 * kk + 1], v4.y, r11);
      r12 = fmaf(acol[4 * kk + 2], v4.z, r12);
      r13 = fmaf(acol[4 * kk + 3], v4.w, r13);
    }
    float r1 = (r10 + r11) + (r12 + r13);

    // rhs s-part (meaningful lanes 28..31): sig*s - v[92+i] + v[96+i]
    float r2v = fmaf(SIG, s_loc, v3 - v2);

    // t1 = r1 + C2 * As^T r2   (4 cross-lane scalars via readlane)
    float acc = 0.f;
    acc = fmaf(acol[28], rl(r2v, 28), acc);
    acc = fmaf(acol[29], rl(r2v, 29), acc);
    acc = fmaf(acol[30], rl(r2v, 30), acc);
    acc = fmaf(acol[31], rl(r2v, 31), acc);
    lst1[t] = fmaf(C2, acc, r1);
    __syncthreads();

    // x = Sinv * t1  (t1 via LDS broadcast, 4-way ILP)
    float xn0 = 0.f, xn1 = 0.f, xn2 = 0.f, xn3 = 0.f;
#pragma unroll
    for (int jj = 0; jj < 16; ++jj) {
      float4 t4 = ((const float4*)lst1)[jj];       // broadcast
      xn0 = fmaf(Cm[4 * jj + 0], t4.x, xn0);
      xn1 = fmaf(Cm[4 * jj + 1], t4.y, xn1);
      xn2 = fmaf(Cm[4 * jj + 2], t4.z, xn2);
      xn3 = fmaf(Cm[4 * jj + 3], t4.w, xn3);
    }
    float xn = (xn0 + xn1) + (xn2 + xn3);
    x_loc = xn;
    lsx[t] = xn;
    __syncthreads();

    // (A x)[r]: arow in regs, x via 2-way-broadcast LDS reads, halves combined
    float pa0 = 0.f, pa1 = 0.f, pa2 = 0.f, pa3 = 0.f;
#pragma unroll
    for (int jj = 0; jj < 8; ++jj) {
      float4 x4 = ((const float4*)(lsx + c0))[jj];
      pa0 = fmaf(arow[4 * jj + 0], x4.x, pa0);
      pa1 = fmaf(arow[4 * jj + 1], x4.y, pa1);
      pa2 = fmaf(arow[4 * jj + 2], x4.z, pa2);
      pa3 = fmaf(arow[4 * jj + 3], x4.w, pa3);
    }
    float pa = (pa0 + pa1) + (pa2 + pa3);
    pa += __shfl_xor(pa, 32);

    // s = C2*(r2 + As x)  (meaningful lanes 28..31)
    float s_new = C2 * (r2v + pa);

    // z,y updates
    { float q1 = xn + y1; z1 = fmaxf(q1, 0.f); y1 = q1 - z1; }
    if (t < 32) {
      float Cx2 = pa - ((t >= 28) ? s_new : 0.f);  // rows 92..95: As x - s
      float q2 = Cx2 + y2; z2 = fminf(q2, bl); y2 = q2 - z2;
    }
    s_loc = s_new;
    float s_from = __shfl(s_new, t - 4);           // lanes 32..35 <- 28..31
    { float q3 = s_from + y3; z3 = fmaxf(q3, 0.f); y3 = q3 - z3; }
  }
  const float xfeas_r = x_loc;   // lsx still holds x_feas

  // ================= MLP gradient =================
  // h-cols 4t..4t+3: x via LDS float4 broadcast, W1 float4 coalesced global
  float4 hacc = make_float4(0.f, 0.f, 0.f, 0.f);
  const float4* W1v = (const float4*)W1;
#pragma unroll 2
  for (int j4 = 0; j4 < 16; ++j4) {
    float4 x4 = ((const float4*)lsx)[j4];          // broadcast
    float xj[4] = {x4.x, x4.y, x4.z, x4.w};
#pragma unroll
    for (int jj = 0; jj < 4; ++jj) {
      float4 w = W1v[(4 * j4 + jj) * 64 + t];
      hacc.x = fmaf(xj[jj], w.x, hacc.x);
      hacc.y = fmaf(xj[jj], w.y, hacc.y);
      hacc.z = fmaf(xj[jj], w.z, hacc.z);
      hacc.w = fmaf(xj[jj], w.w, hacc.w);
    }
  }
  float4 wv = ((const float4*)w2)[t];
  float hx, u0, u1, u2, u3;
  hx = tanhf(hacc.x); u0 = (1.f - hx * hx) * wv.x;
  hx = tanhf(hacc.y); u1 = (1.f - hx * hx) * wv.y;
  hx = tanhf(hacc.z); u2 = (1.f - hx * hx) * wv.z;
  hx = tanhf(hacc.w); u3 = (1.f - hx * hx) * wv.w;
  __syncthreads();                       // lsx readers done
  ((float4*)sbuf)[t] = make_float4(u0, u1, u2, u3);   // sbuf = u[256]
  __syncthreads();

  // g[t] = sum_c W1[t][c]*u[c]; W1T pre-packed: W1T4[c4*64+t] = W1[t][4c4..4c4+3]
  float g0 = 0.f, g1 = 0.f, g2 = 0.f, g3 = 0.f;
  const float4* L4 = (const float4*)W1T;
#pragma unroll 4
  for (int c4 = 0; c4 < 64; ++c4) {
    float4 u4 = ((const float4*)sbuf)[c4];   // broadcast
    float4 w4 = L4[c4 * 64 + t];             // coalesced
    g0 = fmaf(w4.x, u4.x, g0);
    g1 = fmaf(w4.y, u4.y, g1);
    g2 = fmaf(w4.z, u4.z, g2);
    g3 = fmaf(w4.w, u4.w, g3);
  }
  const float gl = (g0 + g1) + (g2 + g3);

  // ================= row norms (from registers) =================
  float pr0 = 0.f, pr1 = 0.f, pr2 = 0.f, pr3 = 0.f;
#pragma unroll
  for (int jj = 0; jj < 8; ++jj) {
    pr0 = fmaf(arow[4 * jj + 0], arow[4 * jj + 0], pr0);
    pr1 = fmaf(arow[4 * jj + 1], arow[4 * jj + 1], pr1);
    pr2 = fmaf(arow[4 * jj + 2], arow[4 * jj + 2], pr2);
    pr3 = fmaf(arow[4 * jj + 3], arow[4 * jj + 3], pr3);
  }
  float pr = (pr0 + pr1) + (pr2 + pr3);
  pr += __shfl_xor(pr, 32);
  __syncthreads();                       // u readers done before lsrn write
  if (t < 32) lsrn[t] = 1.0f / fmaxf(sqrtf(pr), 1e-12f);   // reciprocal norm
  __syncthreads();

  // scale registers (lsA stays raw): acol[k]*=rcp_k, arow[j]*=rcp_r, bn=b_r*rcp_r
  const float rcp_r = lsrn[r];           // 32 distinct addrs: conflict-free
#pragma unroll
  for (int j = 0; j < 32; ++j) arow[j] *= rcp_r;
#pragma unroll
  for (int k = 0; k < 32; ++k) acol[k] *= lsrn[k];   // broadcast reads
  const float bn = (t < 32) ? bl * rcp_r : 0.f;

  // ================= LMO QP: build M, invert =================
  // M col t: (1+eps+sig)I + sum_k rcp_k^2 A[k][t] A[k][:] ; acol already has rcp_k.
#pragma unroll
  for (int i = 0; i < 64; ++i) Cm[i] = 0.f;
#pragma unroll 1
  for (int k = 0; k < 32; ++k) {
    float ak = acol[k] * lsrn[k];        // = rcp_k^2 * A[k][t]
#pragma unroll
    for (int ii = 0; ii < 16; ++ii) {
      float4 a4 = *((const float4*)&lsA[k * LDA + 4 * ii]);  // raw row, broadcast
      Cm[4 * ii + 0] = fmaf(ak, a4.x, Cm[4 * ii + 0]);
      Cm[4 * ii + 1] = fmaf(ak, a4.y, Cm[4 * ii + 1]);
      Cm[4 * ii + 2] = fmaf(ak, a4.z, Cm[4 * ii + 2]);
      Cm[4 * ii + 3] = fmaf(ak, a4.w, Cm[4 * ii + 3]);
    }
  }
#pragma unroll
  for (int i = 0; i < 64; ++i) Cm[i] += (i == t) ? (1.0f + 1e-4f + SIG) : 0.0f;

  gj_invert(Cm, t);

  // ================= LMO ADMM =================
  x_loc = 0.f; z1 = 0.f; y1 = 0.f;
  z2 = (t < 32) ? fminf(0.f, bn) : 0.f;
  y2 = 0.f;

#pragma unroll 1
  for (int it = 0; it < ITRS; ++it) {
    if (t < 32) lsv2[t] = z2 - y2;
    __syncthreads();
    float r10 = fmaf(SIG, x_loc, gl) + (z1 - y1);
    float r11 = 0.f, r12 = 0.f, r13 = 0.f;
#pragma unroll
    for (int kk = 0; kk < 8; ++kk) {
      float4 v4 = ((const float4*)lsv2)[kk];       // broadcast
      r10 = fmaf(acol[4 * kk + 0], v4.x, r10);
      r11 = fmaf(acol[4 * kk + 1], v4.y, r11);
      r12 = fmaf(acol[4 * kk + 2], v4.z, r12);
      r13 = fmaf(acol[4 * kk + 3], v4.w, r13);
    }
    lst1[t] = (r10 + r11) + (r12 + r13);
    __syncthreads();

    float xn0 = 0.f, xn1 = 0.f, xn2 = 0.f, xn3 = 0.f;
#pragma unroll
    for (int jj = 0; jj < 16; ++jj) {
      float4 t4 = ((const float4*)lst1)[jj];       // broadcast
      xn0 = fmaf(Cm[4 * jj + 0], t4.x, xn0);
      xn1 = fmaf(Cm[4 * jj + 1], t4.y, xn1);
      xn2 = fmaf(Cm[4 * jj + 2], t4.z, xn2);
      xn3 = fmaf(Cm[4 * jj + 3], t4.w, xn3);
    }
    float xn = (xn0 + xn1) + (xn2 + xn3);
    x_loc = xn;
    lsx[t] = xn;
    __syncthreads();

    float pa0 = 0.f, pa1 = 0.f, pa2 = 0.f, pa3 = 0.f;
#pragma unroll
    for (int jj = 0; jj < 8; ++jj) {
      float4 x4 = ((const float4*)(lsx + c0))[jj];
      pa0 = fmaf(arow[4 * jj + 0], x4.x, pa0);
      pa1 = fmaf(arow[4 * jj + 1], x4.y, pa1);
      pa2 = fmaf(arow[4 * jj + 2], x4.z, pa2);
      pa3 = fmaf(arow[4 * jj + 3], x4.w, pa3);
    }
    float pa = (pa0 + pa1) + (pa2 + pa3);
    pa += __shfl_xor(pa, 32);

    { float q1 = xn + y1; z1 = fmaxf(q1, 0.f); y1 = q1 - z1; }
    if (t < 32) { float q2 = pa + y2; z2 = fminf(q2, bn); y2 = q2 - z2; }
  }

  out[(size_t)n * 64 + t] = fmaf(0.1f, x_loc, 0.9f * xfeas_r);
}

// ---- W1 re-pack: W1T[c4*256 + t*4 + j] = W1[t*256 + 4*c4 + j] (once) ----
__global__ void w1t_kernel(const float* __restrict__ W1, float* __restrict__ W1T) {
  int idx = blockIdx.x * 256 + threadIdx.x;
  if (idx < 64 * 256) {
    int c4 = idx >> 8, rem = idx & 255, tt = rem >> 2, j = rem & 3;
    W1T[idx] = W1[tt * 256 + 4 * c4 + j];
  }
}

extern "C" void kernel_launch(void* const* d_in, const int* in_sizes, int n_in,
                              void* d_out, int out_size, void* d_ws, size_t ws_size,
                              hipStream_t stream) {
  const float* xraw = (const float*)d_in[0];  // [N,64]
  const float* A    = (const float*)d_in[1];  // [N,32,64]
  const float* b    = (const float*)d_in[2];  // [N,32]
  const float* W1   = (const float*)d_in[3];  // [64,256]
  const float* w2   = (const float*)d_in[4];  // [256]
  float* out = (float*)d_out;

  const int nprob = in_sizes[0] / 64;
  float* W1T = (float*)d_ws;                  // 16384 floats

  w1t_kernel<<<64, 256, 0, stream>>>(W1, W1T);
  fw_kernel<<<nprob, 64, 0, stream>>>(xraw, A, b, W1, W1T, w2, out);
}

// Round 5
// 596.543 us; speedup vs baseline: 1.2051x; 1.0638x over previous
//
#include <hip/hip_runtime.h>
#include <math.h>

// FrankWolfePolicyImprovement, fused: 4096 problems, one wave (64 lanes) each.
// Phases (single kernel, A resident in LDS throughout):
//   1. anchor QP  (Schur-reduced d=68 ADMM, 80 it, Sinv rows in VGPRs)
//   2. tanh MLP gradient
//   3. LMO QP on row-normalized A (normalization folded into registers)
//   4. blend + store
//
// Round-5 design notes:
//  - NO dynamic indexing into register arrays anywhere (rounds 2-4 had
//    acol[k] with rolled k in the S/M builds -> array demoted to AGPR/scratch
//    -> every access inflated to copies; the 2.6x VALU inflation).
//    Builds read A elements from LDS (dynamic LDS indexing is fine).
//  - Live set ~120 (Cm[64]+acol[32]+state): fits arch VGPRs under (64,2).
//    arow dropped; A.x reads rows from LDS (8x b128/iter).
//  - Inversion via symmetric sweep operator: working matrix stays symmetric,
//    pivot row == pivot column == lane-local Cm[0] after rotation. Broadcast
//    = 1 conflict-free ds_write + 16 b128 broadcast reads (replaces 63
//    v_readlane per pivot). After 64 sweeps W = -S^-1; the minus folds free
//    into the x-update FMA input modifier.
//  - Sweep loop: single wave per block + per-wave in-order DS => no barriers.

constexpr float SIG  = 1e-6f;
constexpr float C2   = 1.0f / (4.0f + 1e-6f);   // 1/(4+sigma): slack Schur diag
constexpr int   ITRS = 80;
constexpr int   LDA  = 68;                       // LDS stride for A (16B-aligned rows)

__device__ __forceinline__ float rl(float v, int lane) {
  return __uint_as_float(__builtin_amdgcn_readlane(__float_as_uint(v), lane));
}

// v_rcp_f32 + one Newton step: ~full fp32 precision reciprocal, 4 ops.
__device__ __forceinline__ float rcp_nr(float x) {
  float r = __builtin_amdgcn_rcpf(x);
  return r * fmaf(-x, r, 2.0f);
}

// Symmetric sweep-operator inversion. Lane t holds row t (== col t) of the
// symmetric working matrix W, rotated so the current pivot is local index 0.
// After 64 sweeps: Cm[j] = -Sinv[t][j]. Single-wave blocks; cross-lane data
// moves via lsrow with per-wave in-order DS (no barrier needed).
__device__ __forceinline__ void sweep_invert(float (&Cm)[64], float* lsrow, int t) {
#pragma unroll 1
  for (int p = 0; p < 64; ++p) {
    lsrow[(t - p) & 63] = Cm[0];         // W[t][p]: permutation write, conflict-free
    float alpha = lsrow[0];              // broadcast: W[p][p]
    float inva  = rcp_nr(alpha);
    bool  isP   = (t == p);
    float u0    = Cm[0] * inva;
    float u     = isP ? (1.0f - inva) : u0;   // per-lane sweep multiplier
    float last  = isP ? (-inva)       : u0;   // new column-p entry -> slot 63
#pragma unroll
    for (int j = 0; j < 16; ++j) {
      float4 rp = ((const float4*)lsrow)[j];  // broadcast pivot row chunk
      int m0 = 4 * j;
      if (j) Cm[m0 - 1] = fmaf(-u, rp.x, Cm[m0]);
      Cm[m0 + 0] = fmaf(-u, rp.y, Cm[m0 + 1]);
      Cm[m0 + 1] = fmaf(-u, rp.z, Cm[m0 + 2]);
      Cm[m0 + 2] = fmaf(-u, rp.w, Cm[m0 + 3]);
    }
    Cm[63] = last;
  }
}

__global__ __launch_bounds__(64, 2) void fw_kernel(
    const float* __restrict__ xraw, const float* __restrict__ A,
    const float* __restrict__ b, const float* __restrict__ W1,
    const float* __restrict__ W1T, const float* __restrict__ w2,
    float* __restrict__ out) {
  const int n = blockIdx.x, t = threadIdx.x;
  const float* Ap = A + (size_t)n * 2048;

  __shared__ __align__(16) float lsA[32 * LDA];   // 8704 B, raw A (never rewritten)
  __shared__ __align__(16) float sbuf[256];       // 1024 B, multi-purpose
  float* lst1 = sbuf;            // [64]  ADMM t1 broadcast / sweep lsrow
  float* lsx  = sbuf + 64;       // [64]  ADMM x broadcast
  float* lsv2 = sbuf + 128;      // [32]  ADMM v2 broadcast
  float* lsrn = sbuf + 176;      // [32]  1/rownorm (LMO phase)
  // MLP phase reuses sbuf[0..255] as the u-vector.

  // ---- stage A into LDS (float4 both sides) ----
  const float4* Apv = (const float4*)Ap;
#pragma unroll
  for (int jj = 0; jj < 8; ++jj) {
    float4 a4 = Apv[t + 64 * jj];
    int k = (t >> 4) + 4 * jj;        // row
    int col = 4 * (t & 15);
    *((float4*)&lsA[k * LDA + col]) = a4;
  }
  __syncthreads();

  const int r = t & 31, c0 = (t >> 5) << 5;

  // ================= anchor QP: build S, invert =================
  // S column t: (2+sig)I + A^T A - C2 * As^T As  (As = rows 28..31)
  float Cm[64];
#pragma unroll
  for (int i = 0; i < 64; ++i) Cm[i] = 0.f;
#pragma unroll 1
  for (int k = 0; k < 32; ++k) {
    float wk = (k < 28) ? 1.0f : (1.0f - C2);
    float ak = wk * lsA[k * LDA + t];  // spread read (dynamic k: LDS, not regs)
#pragma unroll
    for (int ii = 0; ii < 16; ++ii) {
      float4 a4 = *((const float4*)&lsA[k * LDA + 4 * ii]);  // broadcast
      Cm[4 * ii + 0] = fmaf(ak, a4.x, Cm[4 * ii + 0]);
      Cm[4 * ii + 1] = fmaf(ak, a4.y, Cm[4 * ii + 1]);
      Cm[4 * ii + 2] = fmaf(ak, a4.z, Cm[4 * ii + 2]);
      Cm[4 * ii + 3] = fmaf(ak, a4.w, Cm[4 * ii + 3]);
    }
  }
#pragma unroll
  for (int i = 0; i < 64; ++i) Cm[i] += (i == t) ? (2.0f + SIG) : 0.0f;

  sweep_invert(Cm, lst1, t);   // Cm[j] = -Sinv[t][j]

  float acol[32];
#pragma unroll
  for (int k = 0; k < 32; ++k) acol[k] = lsA[k * LDA + t];   // A[k][t], static idx

  const float xf = xraw[(size_t)n * 64 + t];
  const float bl = (t < 32) ? b[(size_t)n * 32 + t] : 0.f;

  // ================= anchor ADMM =================
  float x_loc = 0.f, s_loc = 0.f;
  float z1 = 0.f, y1 = 0.f;                       // rows t: l=0,u=inf
  float z2 = (t < 32) ? fminf(0.f, bl) : 0.f;     // rows 64+r: l=-inf,u=b (lanes<32)
  float y2 = 0.f;
  float z3 = 0.f, y3 = 0.f;                       // lanes 32..35: slack bound rows

#pragma unroll 1
  for (int it = 0; it < ITRS; ++it) {
    float v2 = z2 - y2;                            // meaningful lanes<32
    if (t < 32) lsv2[t] = v2;
    float v3 = __shfl(z3 - y3, t + 4);             // lanes 28..31 <- lanes 32..35
    __syncthreads();

    // rhs x-part: sig*x + xf + v1 + A^T v2   (v2 via LDS broadcast, 4-way ILP)
    float r10 = fmaf(SIG, x_loc, xf) + (z1 - y1);
    float r11 = 0.f, r12 = 0.f, r13 = 0.f;
#pragma unroll
    for (int kk = 0; kk < 8; ++kk) {
      float4 v4 = ((const float4*)lsv2)[kk];       // broadcast
      r10 = fmaf(acol[4 * kk + 0], v4.x, r10);
      r11 = fmaf(acol[4 * kk + 1], v4.y, r11);
      r12 = fmaf(acol[4 * kk + 2], v4.z, r12);
      r13 = fmaf(acol[4 * kk + 3], v4.w, r13);
    }
    float r1 = (r10 + r11) + (r12 + r13);

    // rhs s-part (meaningful lanes 28..31): sig*s - v[92+i] + v[96+i]
    float r2v = fmaf(SIG, s_loc, v3 - v2);

    // t1 = r1 + C2 * As^T r2   (4 cross-lane scalars, constant lanes)
    float acc = 0.f;
    acc = fmaf(acol[28], rl(r2v, 28), acc);
    acc = fmaf(acol[29], rl(r2v, 29), acc);
    acc = fmaf(acol[30], rl(r2v, 30), acc);
    acc = fmaf(acol[31], rl(r2v, 31), acc);
    lst1[t] = fmaf(C2, acc, r1);
    __syncthreads();

    // x = Sinv * t1 = -(W * t1): minus folds into FMA input modifier (free)
    float xn0 = 0.f, xn1 = 0.f, xn2 = 0.f, xn3 = 0.f;
#pragma unroll
    for (int jj = 0; jj < 16; ++jj) {
      float4 t4 = ((const float4*)lst1)[jj];       // broadcast
      xn0 = fmaf(-Cm[4 * jj + 0], t4.x, xn0);
      xn1 = fmaf(-Cm[4 * jj + 1], t4.y, xn1);
      xn2 = fmaf(-Cm[4 * jj + 2], t4.z, xn2);
      xn3 = fmaf(-Cm[4 * jj + 3], t4.w, xn3);
    }
    float xn = (xn0 + xn1) + (xn2 + xn3);
    x_loc = xn;
    lsx[t] = xn;
    __syncthreads();

    // (A x)[r]: A row from LDS (spread b128), x via 2-addr broadcast reads
    float pa0 = 0.f, pa1 = 0.f, pa2 = 0.f, pa3 = 0.f;
#pragma unroll
    for (int jj = 0; jj < 8; ++jj) {
      float4 x4 = ((const float4*)(lsx + c0))[jj];
      float4 a4 = *((const float4*)&lsA[r * LDA + c0 + 4 * jj]);
      pa0 = fmaf(a4.x, x4.x, pa0);
      pa1 = fmaf(a4.y, x4.y, pa1);
      pa2 = fmaf(a4.z, x4.z, pa2);
      pa3 = fmaf(a4.w, x4.w, pa3);
    }
    float pa = (pa0 + pa1) + (pa2 + pa3);
    pa += __shfl_xor(pa, 32);

    // s = C2*(r2 + As x)  (meaningful lanes 28..31)
    float s_new = C2 * (r2v + pa);

    // z,y updates
    { float q1 = xn + y1; z1 = fmaxf(q1, 0.f); y1 = q1 - z1; }
    if (t < 32) {
      float Cx2 = pa - ((t >= 28) ? s_new : 0.f);  // rows 92..95: As x - s
      float q2 = Cx2 + y2; z2 = fminf(q2, bl); y2 = q2 - z2;
    }
    s_loc = s_new;
    float s_from = __shfl(s_new, t - 4);           // lanes 32..35 <- 28..31
    { float q3 = s_from + y3; z3 = fmaxf(q3, 0.f); y3 = q3 - z3; }
  }
  const float xfeas_r = x_loc;   // lsx still holds x_feas

  // ================= MLP gradient =================
  float4 hacc = make_float4(0.f, 0.f, 0.f, 0.f);
  const float4* W1v = (const float4*)W1;
#pragma unroll 2
  for (int j4 = 0; j4 < 16; ++j4) {
    float4 x4 = ((const float4*)lsx)[j4];          // broadcast
    float xj[4] = {x4.x, x4.y, x4.z, x4.w};
#pragma unroll
    for (int jj = 0; jj < 4; ++jj) {
      float4 w = W1v[(4 * j4 + jj) * 64 + t];
      hacc.x = fmaf(xj[jj], w.x, hacc.x);
      hacc.y = fmaf(xj[jj], w.y, hacc.y);
      hacc.z = fmaf(xj[jj], w.z, hacc.z);
      hacc.w = fmaf(xj[jj], w.w, hacc.w);
    }
  }
  float4 wv = ((const float4*)w2)[t];
  float hx, u0, u1, u2, u3;
  hx = tanhf(hacc.x); u0 = (1.f - hx * hx) * wv.x;
  hx = tanhf(hacc.y); u1 = (1.f - hx * hx) * wv.y;
  hx = tanhf(hacc.z); u2 = (1.f - hx * hx) * wv.z;
  hx = tanhf(hacc.w); u3 = (1.f - hx * hx) * wv.w;
  __syncthreads();                       // lsx readers done
  ((float4*)sbuf)[t] = make_float4(u0, u1, u2, u3);   // sbuf = u[256]
  __syncthreads();

  // g[t] = sum_c W1[t][c]*u[c]; W1T pre-packed: W1T4[c4*64+t] = W1[t][4c4..4c4+3]
  float g0 = 0.f, g1 = 0.f, g2 = 0.f, g3 = 0.f;
  const float4* L4 = (const float4*)W1T;
#pragma unroll 4
  for (int c4 = 0; c4 < 64; ++c4) {
    float4 u4 = ((const float4*)sbuf)[c4];   // broadcast
    float4 w4 = L4[c4 * 64 + t];             // coalesced
    g0 = fmaf(w4.x, u4.x, g0);
    g1 = fmaf(w4.y, u4.y, g1);
    g2 = fmaf(w4.z, u4.z, g2);
    g3 = fmaf(w4.w, u4.w, g3);
  }
  const float gl = (g0 + g1) + (g2 + g3);

  // ================= row norms (rows from LDS) =================
  float pr0 = 0.f, pr1 = 0.f, pr2 = 0.f, pr3 = 0.f;
#pragma unroll
  for (int jj = 0; jj < 8; ++jj) {
    float4 a4 = *((const float4*)&lsA[r * LDA + c0 + 4 * jj]);
    pr0 = fmaf(a4.x, a4.x, pr0);
    pr1 = fmaf(a4.y, a4.y, pr1);
    pr2 = fmaf(a4.z, a4.z, pr2);
    pr3 = fmaf(a4.w, a4.w, pr3);
  }
  float pr = (pr0 + pr1) + (pr2 + pr3);
  pr += __shfl_xor(pr, 32);
  __syncthreads();                       // u readers done before lsrn write
  if (t < 32) lsrn[t] = 1.0f / fmaxf(sqrtf(pr), 1e-12f);
  __syncthreads();

  const float rcp_r = lsrn[r];           // spread read, conflict-free
  const float bn = (t < 32) ? bl * rcp_r : 0.f;

  // normalized columns in regs (static indices; lsA stays raw)
#pragma unroll
  for (int k = 0; k < 32; ++k) acol[k] = lsA[k * LDA + t] * lsrn[k];

  // ================= LMO QP: build M, invert =================
  // M col t: (1+eps+sig)I + sum_k rcp_k^2 A[k][t] A[k][:]
#pragma unroll
  for (int i = 0; i < 64; ++i) Cm[i] = 0.f;
#pragma unroll 1
  for (int k = 0; k < 32; ++k) {
    float rn = lsrn[k];                  // broadcast (dynamic k: LDS)
    float ak = lsA[k * LDA + t] * rn * rn;
#pragma unroll
    for (int ii = 0; ii < 16; ++ii) {
      float4 a4 = *((const float4*)&lsA[k * LDA + 4 * ii]);  // raw row, broadcast
      Cm[4 * ii + 0] = fmaf(ak, a4.x, Cm[4 * ii + 0]);
      Cm[4 * ii + 1] = fmaf(ak, a4.y, Cm[4 * ii + 1]);
      Cm[4 * ii + 2] = fmaf(ak, a4.z, Cm[4 * ii + 2]);
      Cm[4 * ii + 3] = fmaf(ak, a4.w, Cm[4 * ii + 3]);
    }
  }
#pragma unroll
  for (int i = 0; i < 64; ++i) Cm[i] += (i == t) ? (1.0f + 1e-4f + SIG) : 0.0f;

  sweep_invert(Cm, lst1, t);   // Cm[j] = -Minv[t][j]

  // ================= LMO ADMM =================
  x_loc = 0.f; z1 = 0.f; y1 = 0.f;
  z2 = (t < 32) ? fminf(0.f, bn) : 0.f;
  y2 = 0.f;

#pragma unroll 1
  for (int it = 0; it < ITRS; ++it) {
    if (t < 32) lsv2[t] = z2 - y2;
    __syncthreads();
    float r10 = fmaf(SIG, x_loc, gl) + (z1 - y1);
    float r11 = 0.f, r12 = 0.f, r13 = 0.f;
#pragma unroll
    for (int kk = 0; kk < 8; ++kk) {
      float4 v4 = ((const float4*)lsv2)[kk];       // broadcast
      r10 = fmaf(acol[4 * kk + 0], v4.x, r10);
      r11 = fmaf(acol[4 * kk + 1], v4.y, r11);
      r12 = fmaf(acol[4 * kk + 2], v4.z, r12);
      r13 = fmaf(acol[4 * kk + 3], v4.w, r13);
    }
    lst1[t] = (r10 + r11) + (r12 + r13);
    __syncthreads();

    float xn0 = 0.f, xn1 = 0.f, xn2 = 0.f, xn3 = 0.f;
#pragma unroll
    for (int jj = 0; jj < 16; ++jj) {
      float4 t4 = ((const float4*)lst1)[jj];       // broadcast
      xn0 = fmaf(-Cm[4 * jj + 0], t4.x, xn0);
      xn1 = fmaf(-Cm[4 * jj + 1], t4.y, xn1);
      xn2 = fmaf(-Cm[4 * jj + 2], t4.z, xn2);
      xn3 = fmaf(-Cm[4 * jj + 3], t4.w, xn3);
    }
    float xn = (xn0 + xn1) + (xn2 + xn3);
    x_loc = xn;
    lsx[t] = xn;
    __syncthreads();

    // (An x)[r] = rcp_r * (Araw[r] . x)
    float pa0 = 0.f, pa1 = 0.f, pa2 = 0.f, pa3 = 0.f;
#pragma unroll
    for (int jj = 0; jj < 8; ++jj) {
      float4 x4 = ((const float4*)(lsx + c0))[jj];
      float4 a4 = *((const float4*)&lsA[r * LDA + c0 + 4 * jj]);
      pa0 = fmaf(a4.x, x4.x, pa0);
      pa1 = fmaf(a4.y, x4.y, pa1);
      pa2 = fmaf(a4.z, x4.z, pa2);
      pa3 = fmaf(a4.w, x4.w, pa3);
    }
    float pa = (pa0 + pa1) + (pa2 + pa3);
    pa += __shfl_xor(pa, 32);
    pa *= rcp_r;

    { float q1 = xn + y1; z1 = fmaxf(q1, 0.f); y1 = q1 - z1; }
    if (t < 32) { float q2 = pa + y2; z2 = fminf(q2, bn); y2 = q2 - z2; }
  }

  out[(size_t)n * 64 + t] = fmaf(0.1f, x_loc, 0.9f * xfeas_r);
}

// ---- W1 re-pack: W1T[c4*256 + t*4 + j] = W1[t*256 + 4*c4 + j] (once) ----
__global__ void w1t_kernel(const float* __restrict__ W1, float* __restrict__ W1T) {
  int idx = blockIdx.x * 256 + threadIdx.x;
  if (idx < 64 * 256) {
    int c4 = idx >> 8, rem = idx & 255, tt = rem >> 2, j = rem & 3;
    W1T[idx] = W1[tt * 256 + 4 * c4 + j];
  }
}

extern "C" void kernel_launch(void* const* d_in, const int* in_sizes, int n_in,
                              void* d_out, int out_size, void* d_ws, size_t ws_size,
                              hipStream_t stream) {
  const float* xraw = (const float*)d_in[0];  // [N,64]
  const float* A    = (const float*)d_in[1];  // [N,32,64]
  const float* b    = (const float*)d_in[2];  // [N,32]
  const float* W1   = (const float*)d_in[3];  // [64,256]
  const float* w2   = (const float*)d_in[4];  // [256]
  float* out = (float*)d_out;

  const int nprob = in_sizes[0] / 64;
  float* W1T = (float*)d_ws;                  // 16384 floats

  w1t_kernel<<<64, 256, 0, stream>>>(W1, W1T);
  fw_kernel<<<nprob, 64, 0, stream>>>(xraw, A, b, W1, W1T, w2, out);
}

// Round 6
// 552.853 us; speedup vs baseline: 1.3003x; 1.0790x over previous
//
#include <hip/hip_runtime.h>
#include <math.h>

// FrankWolfePolicyImprovement, fused: 4096 problems, one wave (64 lanes) each.
// Phases (single kernel, A resident in LDS throughout):
//   1. anchor QP  (Schur-reduced d=68 ADMM, 80 it, Sinv rows in VGPRs)
//   2. tanh MLP gradient
//   3. LMO QP on row-normalized A (normalization folded into registers)
//   4. blend + store
//
// Round-6: single change vs round 5 -- __launch_bounds__(64,4).
// Evidence: achieved occupancy has tracked the 2nd launch-bounds arg every
// round ((64,4)->42%, (64,3)->27%, (64,2)->22%) regardless of VGPR headroom,
// and at ~2 waves/SIMD this kernel is latency-bound (long LDS->FMA dependency
// chains, VALUBusy stuck ~63%). Round 5's live set is ~124 regs, which FITS
// the 128-reg budget of 4 waves/EU (round 2's (64,4) failed because ~190 live
// forced an AGPR split + scratch spills). Expect ~2x latency hiding.
//
//  - NO dynamic indexing into register arrays (demotes array to scratch/AGPR).
//  - All wave-internal broadcasts on the LDS pipe (wave-uniform float4 reads),
//    not v_readlane chains (round 3 regression).
//  - Inversion via symmetric sweep operator: pivot row == pivot col, lane-local
//    after rotation; broadcast = 1 conflict-free ds_write + 16 b128 reads.
//    After 64 sweeps W = -S^-1; minus folds into the x-update FMA modifier.
//  - Sweep loop: single wave per block + per-wave in-order DS => no barriers.

constexpr float SIG  = 1e-6f;
constexpr float C2   = 1.0f / (4.0f + 1e-6f);   // 1/(4+sigma): slack Schur diag
constexpr int   ITRS = 80;
constexpr int   LDA  = 68;                       // LDS stride for A (16B-aligned rows)

__device__ __forceinline__ float rl(float v, int lane) {
  return __uint_as_float(__builtin_amdgcn_readlane(__float_as_uint(v), lane));
}

// v_rcp_f32 + one Newton step: ~full fp32 precision reciprocal.
__device__ __forceinline__ float rcp_nr(float x) {
  float r = __builtin_amdgcn_rcpf(x);
  return r * fmaf(-x, r, 2.0f);
}

// Symmetric sweep-operator inversion. Lane t holds row t (== col t) of the
// symmetric working matrix W, rotated so the current pivot is local index 0.
// After 64 sweeps: Cm[j] = -Sinv[t][j]. Single-wave blocks; cross-lane data
// moves via lsrow with per-wave in-order DS (no barrier needed).
__device__ __forceinline__ void sweep_invert(float (&Cm)[64], float* lsrow, int t) {
#pragma unroll 1
  for (int p = 0; p < 64; ++p) {
    lsrow[(t - p) & 63] = Cm[0];         // W[t][p]: permutation write, conflict-free
    float alpha = lsrow[0];              // broadcast: W[p][p]
    float inva  = rcp_nr(alpha);
    bool  isP   = (t == p);
    float u0    = Cm[0] * inva;
    float u     = isP ? (1.0f - inva) : u0;   // per-lane sweep multiplier
    float last  = isP ? (-inva)       : u0;   // new column-p entry -> slot 63
#pragma unroll
    for (int j = 0; j < 16; ++j) {
      float4 rp = ((const float4*)lsrow)[j];  // broadcast pivot row chunk
      int m0 = 4 * j;
      if (j) Cm[m0 - 1] = fmaf(-u, rp.x, Cm[m0]);
      Cm[m0 + 0] = fmaf(-u, rp.y, Cm[m0 + 1]);
      Cm[m0 + 1] = fmaf(-u, rp.z, Cm[m0 + 2]);
      Cm[m0 + 2] = fmaf(-u, rp.w, Cm[m0 + 3]);
    }
    Cm[63] = last;
  }
}

__global__ __launch_bounds__(64, 4) void fw_kernel(
    const float* __restrict__ xraw, const float* __restrict__ A,
    const float* __restrict__ b, const float* __restrict__ W1,
    const float* __restrict__ W1T, const float* __restrict__ w2,
    float* __restrict__ out) {
  const int n = blockIdx.x, t = threadIdx.x;
  const float* Ap = A + (size_t)n * 2048;

  __shared__ __align__(16) float lsA[32 * LDA];   // 8704 B, raw A (never rewritten)
  __shared__ __align__(16) float sbuf[256];       // 1024 B, multi-purpose
  float* lst1 = sbuf;            // [64]  ADMM t1 broadcast / sweep lsrow
  float* lsx  = sbuf + 64;       // [64]  ADMM x broadcast
  float* lsv2 = sbuf + 128;      // [32]  ADMM v2 broadcast
  float* lsrn = sbuf + 176;      // [32]  1/rownorm (LMO phase)
  // MLP phase reuses sbuf[0..255] as the u-vector.

  // ---- stage A into LDS (float4 both sides) ----
  const float4* Apv = (const float4*)Ap;
#pragma unroll
  for (int jj = 0; jj < 8; ++jj) {
    float4 a4 = Apv[t + 64 * jj];
    int k = (t >> 4) + 4 * jj;        // row
    int col = 4 * (t & 15);
    *((float4*)&lsA[k * LDA + col]) = a4;
  }
  __syncthreads();

  const int r = t & 31, c0 = (t >> 5) << 5;

  // ================= anchor QP: build S, invert =================
  // S column t: (2+sig)I + A^T A - C2 * As^T As  (As = rows 28..31)
  float Cm[64];
#pragma unroll
  for (int i = 0; i < 64; ++i) Cm[i] = 0.f;
#pragma unroll 1
  for (int k = 0; k < 32; ++k) {
    float wk = (k < 28) ? 1.0f : (1.0f - C2);
    float ak = wk * lsA[k * LDA + t];  // spread read (dynamic k: LDS, not regs)
#pragma unroll
    for (int ii = 0; ii < 16; ++ii) {
      float4 a4 = *((const float4*)&lsA[k * LDA + 4 * ii]);  // broadcast
      Cm[4 * ii + 0] = fmaf(ak, a4.x, Cm[4 * ii + 0]);
      Cm[4 * ii + 1] = fmaf(ak, a4.y, Cm[4 * ii + 1]);
      Cm[4 * ii + 2] = fmaf(ak, a4.z, Cm[4 * ii + 2]);
      Cm[4 * ii + 3] = fmaf(ak, a4.w, Cm[4 * ii + 3]);
    }
  }
#pragma unroll
  for (int i = 0; i < 64; ++i) Cm[i] += (i == t) ? (2.0f + SIG) : 0.0f;

  sweep_invert(Cm, lst1, t);   // Cm[j] = -Sinv[t][j]

  float acol[32];
#pragma unroll
  for (int k = 0; k < 32; ++k) acol[k] = lsA[k * LDA + t];   // A[k][t], static idx

  const float xf = xraw[(size_t)n * 64 + t];
  const float bl = (t < 32) ? b[(size_t)n * 32 + t] : 0.f;

  // ================= anchor ADMM =================
  float x_loc = 0.f, s_loc = 0.f;
  float z1 = 0.f, y1 = 0.f;                       // rows t: l=0,u=inf
  float z2 = (t < 32) ? fminf(0.f, bl) : 0.f;     // rows 64+r: l=-inf,u=b (lanes<32)
  float y2 = 0.f;
  float z3 = 0.f, y3 = 0.f;                       // lanes 32..35: slack bound rows

#pragma unroll 1
  for (int it = 0; it < ITRS; ++it) {
    float v2 = z2 - y2;                            // meaningful lanes<32
    if (t < 32) lsv2[t] = v2;
    float v3 = __shfl(z3 - y3, t + 4);             // lanes 28..31 <- lanes 32..35
    __syncthreads();

    // rhs x-part: sig*x + xf + v1 + A^T v2   (v2 via LDS broadcast, 4-way ILP)
    float r10 = fmaf(SIG, x_loc, xf) + (z1 - y1);
    float r11 = 0.f, r12 = 0.f, r13 = 0.f;
#pragma unroll
    for (int kk = 0; kk < 8; ++kk) {
      float4 v4 = ((const float4*)lsv2)[kk];       // broadcast
      r10 = fmaf(acol[4 * kk + 0], v4.x, r10);
      r11 = fmaf(acol[4 * kk + 1], v4.y, r11);
      r12 = fmaf(acol[4 * kk + 2], v4.z, r12);
      r13 = fmaf(acol[4 * kk + 3], v4.w, r13);
    }
    float r1 = (r10 + r11) + (r12 + r13);

    // rhs s-part (meaningful lanes 28..31): sig*s - v[92+i] + v[96+i]
    float r2v = fmaf(SIG, s_loc, v3 - v2);

    // t1 = r1 + C2 * As^T r2   (4 cross-lane scalars, constant lanes)
    float acc = 0.f;
    acc = fmaf(acol[28], rl(r2v, 28), acc);
    acc = fmaf(acol[29], rl(r2v, 29), acc);
    acc = fmaf(acol[30], rl(r2v, 30), acc);
    acc = fmaf(acol[31], rl(r2v, 31), acc);
    lst1[t] = fmaf(C2, acc, r1);
    __syncthreads();

    // x = Sinv * t1 = -(W * t1): minus folds into FMA input modifier (free)
    float xn0 = 0.f, xn1 = 0.f, xn2 = 0.f, xn3 = 0.f;
#pragma unroll
    for (int jj = 0; jj < 16; ++jj) {
      float4 t4 = ((const float4*)lst1)[jj];       // broadcast
      xn0 = fmaf(-Cm[4 * jj + 0], t4.x, xn0);
      xn1 = fmaf(-Cm[4 * jj + 1], t4.y, xn1);
      xn2 = fmaf(-Cm[4 * jj + 2], t4.z, xn2);
      xn3 = fmaf(-Cm[4 * jj + 3], t4.w, xn3);
    }
    float xn = (xn0 + xn1) + (xn2 + xn3);
    x_loc = xn;
    lsx[t] = xn;
    __syncthreads();

    // (A x)[r]: A row from LDS (spread b128), x via 2-addr broadcast reads
    float pa0 = 0.f, pa1 = 0.f, pa2 = 0.f, pa3 = 0.f;
#pragma unroll
    for (int jj = 0; jj < 8; ++jj) {
      float4 x4 = ((const float4*)(lsx + c0))[jj];
      float4 a4 = *((const float4*)&lsA[r * LDA + c0 + 4 * jj]);
      pa0 = fmaf(a4.x, x4.x, pa0);
      pa1 = fmaf(a4.y, x4.y, pa1);
      pa2 = fmaf(a4.z, x4.z, pa2);
      pa3 = fmaf(a4.w, x4.w, pa3);
    }
    float pa = (pa0 + pa1) + (pa2 + pa3);
    pa += __shfl_xor(pa, 32);

    // s = C2*(r2 + As x)  (meaningful lanes 28..31)
    float s_new = C2 * (r2v + pa);

    // z,y updates
    { float q1 = xn + y1; z1 = fmaxf(q1, 0.f); y1 = q1 - z1; }
    if (t < 32) {
      float Cx2 = pa - ((t >= 28) ? s_new : 0.f);  // rows 92..95: As x - s
      float q2 = Cx2 + y2; z2 = fminf(q2, bl); y2 = q2 - z2;
    }
    s_loc = s_new;
    float s_from = __shfl(s_new, t - 4);           // lanes 32..35 <- 28..31
    { float q3 = s_from + y3; z3 = fmaxf(q3, 0.f); y3 = q3 - z3; }
  }
  const float xfeas_r = x_loc;   // lsx still holds x_feas

  // ================= MLP gradient =================
  float4 hacc = make_float4(0.f, 0.f, 0.f, 0.f);
  const float4* W1v = (const float4*)W1;
#pragma unroll 2
  for (int j4 = 0; j4 < 16; ++j4) {
    float4 x4 = ((const float4*)lsx)[j4];          // broadcast
    float xj[4] = {x4.x, x4.y, x4.z, x4.w};
#pragma unroll
    for (int jj = 0; jj < 4; ++jj) {
      float4 w = W1v[(4 * j4 + jj) * 64 + t];
      hacc.x = fmaf(xj[jj], w.x, hacc.x);
      hacc.y = fmaf(xj[jj], w.y, hacc.y);
      hacc.z = fmaf(xj[jj], w.z, hacc.z);
      hacc.w = fmaf(xj[jj], w.w, hacc.w);
    }
  }
  float4 wv = ((const float4*)w2)[t];
  float hx, u0, u1, u2, u3;
  hx = tanhf(hacc.x); u0 = (1.f - hx * hx) * wv.x;
  hx = tanhf(hacc.y); u1 = (1.f - hx * hx) * wv.y;
  hx = tanhf(hacc.z); u2 = (1.f - hx * hx) * wv.z;
  hx = tanhf(hacc.w); u3 = (1.f - hx * hx) * wv.w;
  __syncthreads();                       // lsx readers done
  ((float4*)sbuf)[t] = make_float4(u0, u1, u2, u3);   // sbuf = u[256]
  __syncthreads();

  // g[t] = sum_c W1[t][c]*u[c]; W1T pre-packed: W1T4[c4*64+t] = W1[t][4c4..4c4+3]
  float g0 = 0.f, g1 = 0.f, g2 = 0.f, g3 = 0.f;
  const float4* L4 = (const float4*)W1T;
#pragma unroll 4
  for (int c4 = 0; c4 < 64; ++c4) {
    float4 u4 = ((const float4*)sbuf)[c4];   // broadcast
    float4 w4 = L4[c4 * 64 + t];             // coalesced
    g0 = fmaf(w4.x, u4.x, g0);
    g1 = fmaf(w4.y, u4.y, g1);
    g2 = fmaf(w4.z, u4.z, g2);
    g3 = fmaf(w4.w, u4.w, g3);
  }
  const float gl = (g0 + g1) + (g2 + g3);

  // ================= row norms (rows from LDS) =================
  float pr0 = 0.f, pr1 = 0.f, pr2 = 0.f, pr3 = 0.f;
#pragma unroll
  for (int jj = 0; jj < 8; ++jj) {
    float4 a4 = *((const float4*)&lsA[r * LDA + c0 + 4 * jj]);
    pr0 = fmaf(a4.x, a4.x, pr0);
    pr1 = fmaf(a4.y, a4.y, pr1);
    pr2 = fmaf(a4.z, a4.z, pr2);
    pr3 = fmaf(a4.w, a4.w, pr3);
  }
  float pr = (pr0 + pr1) + (pr2 + pr3);
  pr += __shfl_xor(pr, 32);
  __syncthreads();                       // u readers done before lsrn write
  if (t < 32) lsrn[t] = 1.0f / fmaxf(sqrtf(pr), 1e-12f);
  __syncthreads();

  const float rcp_r = lsrn[r];           // spread read, conflict-free
  const float bn = (t < 32) ? bl * rcp_r : 0.f;

  // normalized columns in regs (static indices; lsA stays raw)
#pragma unroll
  for (int k = 0; k < 32; ++k) acol[k] = lsA[k * LDA + t] * lsrn[k];

  // ================= LMO QP: build M, invert =================
  // M col t: (1+eps+sig)I + sum_k rcp_k^2 A[k][t] A[k][:]
#pragma unroll
  for (int i = 0; i < 64; ++i) Cm[i] = 0.f;
#pragma unroll 1
  for (int k = 0; k < 32; ++k) {
    float rn = lsrn[k];                  // broadcast (dynamic k: LDS)
    float ak = lsA[k * LDA + t] * rn * rn;
#pragma unroll
    for (int ii = 0; ii < 16; ++ii) {
      float4 a4 = *((const float4*)&lsA[k * LDA + 4 * ii]);  // raw row, broadcast
      Cm[4 * ii + 0] = fmaf(ak, a4.x, Cm[4 * ii + 0]);
      Cm[4 * ii + 1] = fmaf(ak, a4.y, Cm[4 * ii + 1]);
      Cm[4 * ii + 2] = fmaf(ak, a4.z, Cm[4 * ii + 2]);
      Cm[4 * ii + 3] = fmaf(ak, a4.w, Cm[4 * ii + 3]);
    }
  }
#pragma unroll
  for (int i = 0; i < 64; ++i) Cm[i] += (i == t) ? (1.0f + 1e-4f + SIG) : 0.0f;

  sweep_invert(Cm, lst1, t);   // Cm[j] = -Minv[t][j]

  // ================= LMO ADMM =================
  x_loc = 0.f; z1 = 0.f; y1 = 0.f;
  z2 = (t < 32) ? fminf(0.f, bn) : 0.f;
  y2 = 0.f;

#pragma unroll 1
  for (int it = 0; it < ITRS; ++it) {
    if (t < 32) lsv2[t] = z2 - y2;
    __syncthreads();
    float r10 = fmaf(SIG, x_loc, gl) + (z1 - y1);
    float r11 = 0.f, r12 = 0.f, r13 = 0.f;
#pragma unroll
    for (int kk = 0; kk < 8; ++kk) {
      float4 v4 = ((const float4*)lsv2)[kk];       // broadcast
      r10 = fmaf(acol[4 * kk + 0], v4.x, r10);
      r11 = fmaf(acol[4 * kk + 1], v4.y, r11);
      r12 = fmaf(acol[4 * kk + 2], v4.z, r12);
      r13 = fmaf(acol[4 * kk + 3], v4.w, r13);
    }
    lst1[t] = (r10 + r11) + (r12 + r13);
    __syncthreads();

    float xn0 = 0.f, xn1 = 0.f, xn2 = 0.f, xn3 = 0.f;
#pragma unroll
    for (int jj = 0; jj < 16; ++jj) {
      float4 t4 = ((const float4*)lst1)[jj];       // broadcast
      xn0 = fmaf(-Cm[4 * jj + 0], t4.x, xn0);
      xn1 = fmaf(-Cm[4 * jj + 1], t4.y, xn1);
      xn2 = fmaf(-Cm[4 * jj + 2], t4.z, xn2);
      xn3 = fmaf(-Cm[4 * jj + 3], t4.w, xn3);
    }
    float xn = (xn0 + xn1) + (xn2 + xn3);
    x_loc = xn;
    lsx[t] = xn;
    __syncthreads();

    // (An x)[r] = rcp_r * (Araw[r] . x)
    float pa0 = 0.f, pa1 = 0.f, pa2 = 0.f, pa3 = 0.f;
#pragma unroll
    for (int jj = 0; jj < 8; ++jj) {
      float4 x4 = ((const float4*)(lsx + c0))[jj];
      float4 a4 = *((const float4*)&lsA[r * LDA + c0 + 4 * jj]);
      pa0 = fmaf(a4.x, x4.x, pa0);
      pa1 = fmaf(a4.y, x4.y, pa1);
      pa2 = fmaf(a4.z, x4.z, pa2);
      pa3 = fmaf(a4.w, x4.w, pa3);
    }
    float pa = (pa0 + pa1) + (pa2 + pa3);
    pa += __shfl_xor(pa, 32);
    pa *= rcp_r;

    { float q1 = xn + y1; z1 = fmaxf(q1, 0.f); y1 = q1 - z1; }
    if (t < 32) { float q2 = pa + y2; z2 = fminf(q2, bn); y2 = q2 - z2; }
  }

  out[(size_t)n * 64 + t] = fmaf(0.1f, x_loc, 0.9f * xfeas_r);
}

// ---- W1 re-pack: W1T[c4*256 + t*4 + j] = W1[t*256 + 4*c4 + j] (once) ----
__global__ void w1t_kernel(const float* __restrict__ W1, float* __restrict__ W1T) {
  int idx = blockIdx.x * 256 + threadIdx.x;
  if (idx < 64 * 256) {
    int c4 = idx >> 8, rem = idx & 255, tt = rem >> 2, j = rem & 3;
    W1T[idx] = W1[tt * 256 + 4 * c4 + j];
  }
}

extern "C" void kernel_launch(void* const* d_in, const int* in_sizes, int n_in,
                              void* d_out, int out_size, void* d_ws, size_t ws_size,
                              hipStream_t stream) {
  const float* xraw = (const float*)d_in[0];  // [N,64]
  const float* A    = (const float*)d_in[1];  // [N,32,64]
  const float* b    = (const float*)d_in[2];  // [N,32]
  const float* W1   = (const float*)d_in[3];  // [64,256]
  const float* w2   = (const float*)d_in[4];  // [256]
  float* out = (float*)d_out;

  const int nprob = in_sizes[0] / 64;
  float* W1T = (float*)d_ws;                  // 16384 floats

  w1t_kernel<<<64, 256, 0, stream>>>(W1, W1T);
  fw_kernel<<<nprob, 64, 0, stream>>>(xraw, A, b, W1, W1T, w2, out);
}